// Round 2
// baseline (291.557 us; speedup 1.0000x reference)
//
#include <hip/hip_runtime.h>

// B=8, S=1024, D=1024, H=16, P=64. FP32 I/O, bf16 MFMA compute.
// convert W (+acts) -> bf16 | pipelined 256x256 QKV GEMM (4-slot, counted
// vmcnt) | MFMA batch-softmax attention | pipelined final GEMM + sigmoid.

using short8   = __attribute__((ext_vector_type(8))) short;    // 8 bf16
using floatx4  = __attribute__((ext_vector_type(4))) float;    // MFMA acc 16x16
using floatx16 = __attribute__((ext_vector_type(16))) float;   // MFMA acc 32x32

__device__ __forceinline__ float bf2f(unsigned short u) {
    return __uint_as_float(((unsigned)u) << 16);
}
__device__ __forceinline__ unsigned short f2bf(float f) {   // RNE
    unsigned u = __float_as_uint(f);
    u += 0x7fffu + ((u >> 16) & 1u);
    return (unsigned short)(u >> 16);
}
// two fp32 -> packed bf16 pair (truncation) in one v_perm: lo16=f0, hi16=f1
__device__ __forceinline__ unsigned pack_trunc(float f0, float f1) {
    return __builtin_amdgcn_perm(__float_as_uint(f1), __float_as_uint(f0), 0x07060302u);
}
__device__ __forceinline__ void async_ld16(const void* g, void* l) {
    __builtin_amdgcn_global_load_lds(
        (const __attribute__((address_space(1))) unsigned int*)g,
        (__attribute__((address_space(3))) unsigned int*)l, 16, 0, 0);
}

// ---------------------------------------------------------------------------
// fp32 -> bf16 (RNE) converters
// ---------------------------------------------------------------------------
__device__ __forceinline__ void conv8(const float* src, unsigned short* d, size_t i) {
    float4 a = *(const float4*)(src + i);
    float4 b = *(const float4*)(src + i + 4);
    uint4 o;
    o.x = ((unsigned)f2bf(a.y) << 16) | f2bf(a.x);
    o.y = ((unsigned)f2bf(a.w) << 16) | f2bf(a.z);
    o.z = ((unsigned)f2bf(b.y) << 16) | f2bf(b.x);
    o.w = ((unsigned)f2bf(b.w) << 16) | f2bf(b.z);
    *(uint4*)(d + i) = o;
}

__global__ __launch_bounds__(256) void convert_weights(
    const float* __restrict__ w0, const float* __restrict__ w1,
    const float* __restrict__ w2, const float* __restrict__ w3,
    unsigned short* __restrict__ dst)
{
    const float* srcs[4] = {w0, w1, w2, w3};
    conv8(srcs[blockIdx.y], dst + (size_t)blockIdx.y * (1024u * 1024u),
          ((size_t)blockIdx.x * 256 + threadIdx.x) * 8);
}

__global__ __launch_bounds__(256) void convert_acts(
    const float* __restrict__ a0, const float* __restrict__ a1,
    const float* __restrict__ a2, unsigned short* __restrict__ dst)
{
    const float* srcs[3] = {a0, a1, a2};
    conv8(srcs[blockIdx.y], dst + (size_t)blockIdx.y * ((size_t)8192 * 1024),
          ((size_t)blockIdx.x * 256 + threadIdx.x) * 8);
}

// ---------------------------------------------------------------------------
// OLD 128x128 GEMM (m97 structure) — kept only as the small-workspace
// fallback path (f32 A staged directly). Unchanged.
// ---------------------------------------------------------------------------
template<bool AF32, bool SIG>
__global__ __launch_bounds__(256) void gemm128(
    const void* __restrict__ A0, const void* __restrict__ A1, const void* __restrict__ A2,
    const unsigned short* __restrict__ W0, const unsigned short* __restrict__ W1,
    const unsigned short* __restrict__ W2,
    const float* __restrict__ b0, const float* __restrict__ b1, const float* __restrict__ b2,
    void* __restrict__ C0, void* __restrict__ C1, void* __restrict__ C2)
{
    const int z = blockIdx.z;
    const void* Ap = (z == 0) ? A0 : (z == 1) ? A1 : A2;
    const unsigned short* W = (z == 0) ? W0 : (z == 1) ? W1 : W2;
    const float* bias = (z == 0) ? b0 : (z == 1) ? b1 : b2;
    void* Cp = (z == 0) ? C0 : (z == 1) ? C1 : C2;

    constexpr int Kd = 1024, Nd = 1024;
    const int t = threadIdx.x;
    const int w = t >> 6, lane = t & 63;
    const int l15 = lane & 15, quad = lane >> 4;
    const int blockM = blockIdx.x * 128;
    const int blockN = blockIdx.y * 128;
    const int wy = w >> 1, wx = w & 1;

    __shared__ unsigned short Bs[128 * 32];
    constexpr int ABYTES = AF32 ? (128 * 32 * 4) : (128 * 32 * 2);
    __shared__ __align__(16) unsigned char AsRaw[ABYTES];
    float* AsF = (float*)AsRaw;
    unsigned short* AsB = (unsigned short*)AsRaw;

    const int br  = lane >> 2;
    const int bg  = (lane & 3) ^ (br & 3);
    const unsigned short* Bsrc0 = W + (size_t)(blockN + w * 32 + br) * Kd + bg * 8;
    const unsigned short* Bsrc1 = Bsrc0 + (size_t)16 * Kd;
    unsigned short* Bdst0 = &Bs[(w * 2 + 0) * 512];
    unsigned short* Bdst1 = &Bs[(w * 2 + 1) * 512];

    const int ar = lane >> 3;
    const int ag = (lane & 7) ^ (ar & 7);
    const float* AsrcF[4];
    float* AdstF[4];
    const unsigned short* AsrcB0 = nullptr; const unsigned short* AsrcB1 = nullptr;
    unsigned short* AdstB0 = nullptr; unsigned short* AdstB1 = nullptr;
    if (AF32) {
        #pragma unroll
        for (int j = 0; j < 4; ++j) {
            AsrcF[j] = (const float*)Ap + (size_t)(blockM + w * 32 + j * 8 + ar) * Kd + ag * 4;
            AdstF[j] = AsF + (w * 4 + j) * 256;
        }
    } else {
        AsrcB0 = (const unsigned short*)Ap + (size_t)(blockM + w * 32 + br) * Kd + bg * 8;
        AsrcB1 = AsrcB0 + (size_t)16 * Kd;
        AdstB0 = &AsB[(w * 2 + 0) * 512];
        AdstB1 = &AsB[(w * 2 + 1) * 512];
    }

    floatx4 acc[4][4] = {};

    for (int k0 = 0; k0 < Kd; k0 += 32) {
        if (AF32) {
            #pragma unroll
            for (int j = 0; j < 4; ++j) async_ld16(AsrcF[j] + k0, AdstF[j]);
        } else {
            async_ld16(AsrcB0 + k0, AdstB0);
            async_ld16(AsrcB1 + k0, AdstB1);
        }
        async_ld16(Bsrc0 + k0, Bdst0);
        async_ld16(Bsrc1 + k0, Bdst1);
        __syncthreads();

        short8 af[4], bfr[4];
        #pragma unroll
        for (int mt = 0; mt < 4; ++mt) {
            const int row = wy * 64 + mt * 16 + l15;
            if (AF32) {
                const int r7 = l15 & 7;
                const float* ap = AsF + row * 32;
                float4 lo = *(const float4*)(ap + (((quad * 2 + 0) ^ r7) * 4));
                float4 hi = *(const float4*)(ap + (((quad * 2 + 1) ^ r7) * 4));
                union { unsigned u[4]; short8 s; } cv;
                cv.u[0] = pack_trunc(lo.x, lo.y);
                cv.u[1] = pack_trunc(lo.z, lo.w);
                cv.u[2] = pack_trunc(hi.x, hi.y);
                cv.u[3] = pack_trunc(hi.z, hi.w);
                af[mt] = cv.s;
            } else {
                af[mt] = *(const short8*)&AsB[row * 32 + (quad ^ (l15 & 3)) * 8];
            }
        }
        #pragma unroll
        for (int nt = 0; nt < 4; ++nt) {
            const int row = wx * 64 + nt * 16 + l15;
            bfr[nt] = *(const short8*)&Bs[row * 32 + (quad ^ (l15 & 3)) * 8];
        }
        #pragma unroll
        for (int mt = 0; mt < 4; ++mt)
            #pragma unroll
            for (int nt = 0; nt < 4; ++nt)
                acc[mt][nt] = __builtin_amdgcn_mfma_f32_16x16x32_bf16(af[mt], bfr[nt], acc[mt][nt], 0, 0, 0);
        __syncthreads();
    }

    #pragma unroll
    for (int nt = 0; nt < 4; ++nt) {
        const int col = blockN + wx * 64 + nt * 16 + l15;
        const float bv = bias[col];
        #pragma unroll
        for (int mt = 0; mt < 4; ++mt) {
            const int row = blockM + wy * 64 + mt * 16 + quad * 4;
            #pragma unroll
            for (int r = 0; r < 4; ++r) {
                float v = acc[mt][nt][r] + bv;
                if (SIG) {
                    v = 1.0f / (1.0f + __expf(-v));
                    ((float*)Cp)[(size_t)(row + r) * Nd + col] = v;
                } else {
                    ((unsigned short*)Cp)[(size_t)(row + r) * Nd + col] = f2bf(v);
                }
            }
        }
    }
}

// ---------------------------------------------------------------------------
// 256x256-tile pipelined GEMM. C = A.W^T + bias, A bf16 [M][1024],
// W bf16 [N][1024]. BK=32, 4 LDS slots (128 KiB), 512 threads = 8 waves
// (2 M x 4 N), per-wave 128x64 output via mfma_f32_32x32x16_bf16 acc[4][2].
//
// Pipeline (phase t computes K-tile t from slot t&3, stages tile t+3):
//   [12 ds_read_b128] [4 global_load_lds 16B -> slot (t+3)&3]
//   [s_waitcnt vmcnt(8)]  <- waits tile t+1 only; >=8 loads stay in flight
//   [s_barrier] [setprio1; 16 MFMA; setprio0] [s_barrier]
// Slot safety: in-flight stages touch slots (t+1..t+3)&3 != t&3. Barrier B
// (after MFMA, i.e. after each wave's lgkm drain) orders all ds_reads of
// slot t&3 before any wave issues the stage of tile t+4 (same slot).
// Tail: vmcnt steps 8 -> 4 -> 0 as staging stops.
//
// LDS layout per slot per matrix: 256 rows x 32 k, two rows per 128B line
// (L = r>>1), 16B granules swizzled G' = ((r&1)*4 + g) ^ (L&7). Fragment
// reads (row=l&31, k-granule=ks*2+(l>>5)) then spread 64 lanes evenly over
// all 8 granule positions (conflict-free b128). global_load_lds writes the
// LDS linearly; the INVERSE permutation is applied to the global source
// address (both-sides-or-neither).
// ---------------------------------------------------------------------------
#define VM8 do { asm volatile("s_waitcnt vmcnt(8)" ::: "memory"); \
                 __builtin_amdgcn_sched_barrier(0); } while (0)
#define VM4 do { asm volatile("s_waitcnt vmcnt(4)" ::: "memory"); \
                 __builtin_amdgcn_sched_barrier(0); } while (0)
#define VM0 do { asm volatile("s_waitcnt vmcnt(0)" ::: "memory"); \
                 __builtin_amdgcn_sched_barrier(0); } while (0)
#define BARRIER __builtin_amdgcn_s_barrier()

#define STAGE_T(s, k0) do { \
    async_ld16(srcA[0] + (k0), &lds[s][0][dA0]); \
    async_ld16(srcA[1] + (k0), &lds[s][0][dA1]); \
    async_ld16(srcB[0] + (k0), &lds[s][1][dA0]); \
    async_ld16(srcB[1] + (k0), &lds[s][1][dA1]); \
} while (0)

#define PHASE_T(s, STG, VMW) do { \
    short8 afr[4][2], bfr2[2][2]; \
    const unsigned short* As_ = lds[s][0]; \
    const unsigned short* Bs_ = lds[s][1]; \
    _Pragma("unroll") \
    for (int mf = 0; mf < 4; ++mf) \
      _Pragma("unroll") \
      for (int ks = 0; ks < 2; ++ks) \
        afr[mf][ks] = *(const short8*)&As_[aoff[mf][ks]]; \
    _Pragma("unroll") \
    for (int nf = 0; nf < 2; ++nf) \
      _Pragma("unroll") \
      for (int ks = 0; ks < 2; ++ks) \
        bfr2[nf][ks] = *(const short8*)&Bs_[boff[nf][ks]]; \
    STG; \
    VMW; \
    BARRIER; \
    __builtin_amdgcn_s_setprio(1); \
    _Pragma("unroll") \
    for (int ks = 0; ks < 2; ++ks) \
      _Pragma("unroll") \
      for (int mf = 0; mf < 4; ++mf) \
        _Pragma("unroll") \
        for (int nf = 0; nf < 2; ++nf) \
          acc[mf][nf] = __builtin_amdgcn_mfma_f32_32x32x16_bf16( \
              afr[mf][ks], bfr2[nf][ks], acc[mf][nf], 0, 0, 0); \
    __builtin_amdgcn_s_setprio(0); \
    BARRIER; \
} while (0)

template<bool SIG>
__global__ __launch_bounds__(512, 2) void gemm256(
    const unsigned short* __restrict__ A0, const unsigned short* __restrict__ A1,
    const unsigned short* __restrict__ A2,
    const unsigned short* __restrict__ W0, const unsigned short* __restrict__ W1,
    const unsigned short* __restrict__ W2,
    const float* __restrict__ b0, const float* __restrict__ b1, const float* __restrict__ b2,
    void* __restrict__ C0, void* __restrict__ C1, void* __restrict__ C2)
{
    const int z = blockIdx.z;
    const unsigned short* A = (z == 0) ? A0 : (z == 1) ? A1 : A2;
    const unsigned short* W = (z == 0) ? W0 : (z == 1) ? W1 : W2;
    const float* bias = (z == 0) ? b0 : (z == 1) ? b1 : b2;
    void* Cp = (z == 0) ? C0 : (z == 1) ? C1 : C2;

    constexpr int Kd = 1024;
    const int t = threadIdx.x;
    const int w = t >> 6, l = t & 63;
    const int wy = w >> 2, wx = w & 3;          // 2 x 4 wave grid
    const int l31 = l & 31, h5 = l >> 5;
    const int blockM = blockIdx.x * 256;
    const int blockN = blockIdx.y * 256;

    __shared__ __align__(16) unsigned short lds[4][2][8192];  // 128 KiB

    // -- staging source pointers (inverse-swizzled global addresses) --
    // granule q = i*512 + w*64 + lane: L=q>>3, G'=q&7, Graw=G'^(L&7),
    // r = 2L + (Graw>>2), g = Graw&3  -> src elem (row0+r)*1024 + k0 + g*8
    const unsigned short* srcA[2];
    const unsigned short* srcB[2];
    #pragma unroll
    for (int i = 0; i < 2; ++i) {
        const int q  = i * 512 + w * 64 + l;
        const int L  = q >> 3;
        const int Gr = (q & 7) ^ (L & 7);
        const int r  = L * 2 + (Gr >> 2);
        const int g  = Gr & 3;
        srcA[i] = A + (size_t)(blockM + r) * Kd + g * 8;
        srcB[i] = W + (size_t)(blockN + r) * Kd + g * 8;
    }
    const int dA0 = (0 * 512 + w * 64) * 8;   // wave-uniform LDS short offsets
    const int dA1 = (1 * 512 + w * 64) * 8;

    // -- ds_read fragment offsets (swizzled) --
    // A-frag (32x32x16): row = m0 + l31, k = ks*16 + h5*8 + j
    const int Lh  = l31 >> 1;
    const int la7 = Lh & 7;
    const int e4  = (l & 1) * 4;
    int aoff[4][2], boff[2][2];
    #pragma unroll
    for (int mf = 0; mf < 4; ++mf)
        #pragma unroll
        for (int ks = 0; ks < 2; ++ks)
            aoff[mf][ks] = (wy * 64 + mf * 16 + Lh) * 64 + ((e4 + ks * 2 + h5) ^ la7) * 8;
    #pragma unroll
    for (int nf = 0; nf < 2; ++nf)
        #pragma unroll
        for (int ks = 0; ks < 2; ++ks)
            boff[nf][ks] = (wx * 32 + nf * 16 + Lh) * 64 + ((e4 + ks * 2 + h5) ^ la7) * 8;

    floatx16 acc[4][2] = {};

    // -- prologue: stage tiles 0,1,2; wait tile 0 --
    STAGE_T(0, 0); STAGE_T(1, 32); STAGE_T(2, 64);
    VM8;        // 12 outstanding -> wait tile 0 landed (t1,t2 in flight)
    BARRIER;

    int k0 = 96;
    #pragma unroll 1
    for (int tt = 0; tt < 28; tt += 4) {
        PHASE_T(0, STAGE_T(3, k0), VM8); k0 += 32;
        PHASE_T(1, STAGE_T(0, k0), VM8); k0 += 32;
        PHASE_T(2, STAGE_T(1, k0), VM8); k0 += 32;
        PHASE_T(3, STAGE_T(2, k0), VM8); k0 += 32;
    }
    // t = 28..31 (k0 == 992 stages tile 31)
    PHASE_T(0, STAGE_T(3, k0), VM8);
    PHASE_T(1, (void)0, VM4);
    PHASE_T(2, (void)0, VM0);
    PHASE_T(3, (void)0, (void)0);

    // -- epilogue: bias + store. C layout: col=l31, row=(rg&3)+8*(rg>>2)+4*h5
    const int colBase = blockN + wx * 64 + l31;
    const float bv0 = bias[colBase];
    const float bv1 = bias[colBase + 32];
    #pragma unroll
    for (int mf = 0; mf < 4; ++mf) {
        const int row0 = blockM + wy * 128 + mf * 32 + h5 * 4;
        #pragma unroll
        for (int nf = 0; nf < 2; ++nf) {
            const float bb = nf ? bv1 : bv0;
            const int col = colBase + nf * 32;
            #pragma unroll
            for (int rg = 0; rg < 16; ++rg) {
                const int row = row0 + (rg & 3) + 8 * (rg >> 2);
                float v = acc[mf][nf][rg] + bb;
                if (SIG) {
                    v = 1.0f / (1.0f + __expf(-v));
                    ((float*)Cp)[(size_t)row * 1024 + col] = v;
                } else {
                    ((unsigned short*)Cp)[(size_t)row * 1024 + col] = f2bf(v);
                }
            }
        }
    }
}

// ---------------------------------------------------------------------------
// MFMA attention. grid = (S=1024, 2 p-halves), block = 512 (wave = b).
// (unchanged — see earlier round comments)
// ---------------------------------------------------------------------------
__global__ __launch_bounds__(512) void attn_mfma(
    const unsigned short* __restrict__ Q,
    const unsigned short* __restrict__ Kt,
    const unsigned short* __restrict__ Vt,
    unsigned short* __restrict__ O2)
{
    constexpr int VOFF = 0;        // shorts
    constexpr int UOFF = 9216;     // shorts (16B-aligned: 18432 B)
    constexpr int QOFF = UOFF + 8192;
    __shared__ __align__(16) unsigned short lds[UOFF + 18432];

    const int s  = blockIdx.x;
    const int ph = blockIdx.y;
    const int t  = threadIdx.x;
    const int w  = t >> 6;          // wave = b
    const int l  = t & 63;
    const int l15 = l & 15, l31 = l & 31, half = l >> 5, quad = l >> 4;

    const size_t gb = ((size_t)w * 1024 + s) * 1024;  // shorts

    // ---- load phase ----
    {
        const unsigned* vg = (const unsigned*)(Vt + gb);
        unsigned* vd = (unsigned*)lds;            // Vt dword base
        #pragma unroll
        for (int it = 0; it < 8; ++it) {
            const int h = it * 2 + half;
            vd[w * 576 + h * 36 + l31] = vg[h * 32 + l31];
        }
        const unsigned short* kg = Kt + gb;
        unsigned* kd = (unsigned*)(lds + UOFF);
        #pragma unroll
        for (int h2 = 0; h2 < 8; ++h2) {
            unsigned klo = kg[(2 * h2) * 64 + l];
            unsigned khi = kg[(2 * h2 + 1) * 64 + l];
            kd[w * 512 + l * 8 + h2] = klo | (khi << 16);
        }
        const unsigned short* qg = Q + gb + ph * 32;
        unsigned* qd = (unsigned*)(lds + QOFF);
        #pragma unroll
        for (int it = 0; it < 4; ++it) {
            const int h = it * 4 + half * 2;
            unsigned qlo = qg[h * 64 + l31];
            unsigned qhi = qg[(h + 1) * 64 + l31];
            qd[w * 256 + l31 * 8 + it * 2 + half] = qlo | (qhi << 16);
        }
    }
    __syncthreads();

    // ---- scores: A=K (m=q), B=Q (n=p), K=16=h ----
    floatx16 sc[2];
    {
        short8 qf = *(const short8*)&lds[QOFF + w * 512 + l31 * 16 + half * 8];
        short8 kf0 = *(const short8*)&lds[UOFF + w * 1024 + l31 * 16 + half * 8];
        short8 kf1 = *(const short8*)&lds[UOFF + w * 1024 + (32 + l31) * 16 + half * 8];
        floatx16 z = {};
        sc[0] = __builtin_amdgcn_mfma_f32_32x32x16_bf16(kf0, qf, z, 0, 0, 0);
        sc[1] = __builtin_amdgcn_mfma_f32_32x32x16_bf16(kf1, qf, z, 0, 0, 0);
    }
    __syncthreads();   // K/Q region dead -> reuse as Sexp

    // ---- exp + Sexp[p][q] writes (p = l31, q from C layout) ----
    {
        unsigned short* sx = lds + UOFF + w * 2304 + l31 * 72;
        #pragma unroll
        for (int nt = 0; nt < 2; ++nt) {
            #pragma unroll
            for (int rg = 0; rg < 4; ++rg) {
                float e0 = __expf(sc[nt][4 * rg + 0] * 0.125f);
                float e1 = __expf(sc[nt][4 * rg + 1] * 0.125f);
                float e2 = __expf(sc[nt][4 * rg + 2] * 0.125f);
                float e3 = __expf(sc[nt][4 * rg + 3] * 0.125f);
                uint2 pk = { pack_trunc(e0, e1), pack_trunc(e2, e3) };
                const int q0 = nt * 32 + rg * 8 + half * 4;
                *(uint2*)&sx[q0] = pk;
            }
        }
    }
    __syncthreads();

    // ---- batch-softmax denominators: thread owns (p=t&31, q0=(t>>5)*4) ----
    {
        const int p  = t & 31;
        const int q0 = (t >> 5) * 4;
        unsigned short* base = lds + UOFF + p * 72 + q0;
        float fv[8][4];
        float den0 = 0.f, den1 = 0.f, den2 = 0.f, den3 = 0.f;
        #pragma unroll
        for (int b = 0; b < 8; ++b) {
            uint2 v = *(const uint2*)&base[b * 2304];
            fv[b][0] = bf2f((unsigned short)(v.x & 0xffff));
            fv[b][1] = bf2f((unsigned short)(v.x >> 16));
            fv[b][2] = bf2f((unsigned short)(v.y & 0xffff));
            fv[b][3] = bf2f((unsigned short)(v.y >> 16));
            den0 += fv[b][0]; den1 += fv[b][1]; den2 += fv[b][2]; den3 += fv[b][3];
        }
        const float r0 = __builtin_amdgcn_rcpf(den0);
        const float r1 = __builtin_amdgcn_rcpf(den1);
        const float r2 = __builtin_amdgcn_rcpf(den2);
        const float r3 = __builtin_amdgcn_rcpf(den3);
        #pragma unroll
        for (int b = 0; b < 8; ++b) {
            uint2 pk = { pack_trunc(fv[b][0] * r0, fv[b][1] * r1),
                         pack_trunc(fv[b][2] * r2, fv[b][3] * r3) };
            *(uint2*)&base[b * 2304] = pk;
        }
    }
    __syncthreads();

    // ---- PV: A=weights[p][q], B=Vt[h][q]; out[p][h] ----
    floatx4 o[2] = {};
    #pragma unroll
    for (int qc = 0; qc < 2; ++qc) {
        short8 vf = *(const short8*)&lds[VOFF + w * 1152 + l15 * 72 + qc * 32 + quad * 8];
        #pragma unroll
        for (int mt = 0; mt < 2; ++mt) {
            short8 wf = *(const short8*)&lds[UOFF + w * 2304 + (mt * 16 + l15) * 72 + qc * 32 + quad * 8];
            o[mt] = __builtin_amdgcn_mfma_f32_16x16x32_bf16(wf, vf, o[mt], 0, 0, 0);
        }
    }
    {
        unsigned short* ol = lds + UOFF + w * 2304 + l15 * 36;
        #pragma unroll
        for (int mt = 0; mt < 2; ++mt) {
            uint2 pk = { pack_trunc(o[mt][0], o[mt][1]), pack_trunc(o[mt][2], o[mt][3]) };
            *(uint2*)&ol[mt * 16 + quad * 4] = pk;
        }
    }
    __syncthreads();

    // ---- coalesced store: per wave (b), 256 dwords ----
    {
        unsigned* outdw = (unsigned*)O2;
        const unsigned* ol = (const unsigned*)(lds + UOFF + w * 2304);
        const size_t gdw = ((size_t)w * 1024 + s) * 512 + ph * 16;
        #pragma unroll
        for (int i = 0; i < 4; ++i) {
            const int d = i * 64 + l;
            const int h = d >> 4, pq = d & 15;
            outdw[gdw + h * 32 + pq] = ol[h * 18 + pq];
        }
    }
}

// ---------------------------------------------------------------------------
extern "C" void kernel_launch(void* const* d_in, const int* in_sizes, int n_in,
                              void* d_out, int out_size, void* d_ws, size_t ws_size,
                              hipStream_t stream) {
    const float* query = (const float*)d_in[0];
    const float* key_  = (const float*)d_in[1];
    const float* value = (const float*)d_in[2];
    const float* Wq = (const float*)d_in[3];
    const float* bq = (const float*)d_in[4];
    const float* Wk = (const float*)d_in[5];
    const float* bk = (const float*)d_in[6];
    const float* Wv = (const float*)d_in[7];
    const float* bv = (const float*)d_in[8];
    const float* Wo = (const float*)d_in[9];
    const float* bo = (const float*)d_in[10];

    const size_t WN = (size_t)1024 * 1024;
    const size_t MN = (size_t)8192 * 1024;

    unsigned short* Wbf = (unsigned short*)d_ws;
    unsigned short* Wq_bf = Wbf;
    unsigned short* Wk_bf = Wbf + WN;
    unsigned short* Wv_bf = Wbf + 2 * WN;
    unsigned short* Wo_bf = Wbf + 3 * WN;

    convert_weights<<<dim3(512, 4), dim3(256), 0, stream>>>(Wq, Wk, Wv, Wo, Wbf);

    const bool big = ws_size >= (4 * WN + 6 * MN) * sizeof(unsigned short); // 104 MB

    unsigned short* Qb; unsigned short* Kb; unsigned short* Vb;
    if (big) {
        unsigned short* abf = Wbf + 4 * WN;
        Qb = abf + 3 * MN; Kb = Qb + MN; Vb = Kb + MN;
        convert_acts<<<dim3(4096, 3), dim3(256), 0, stream>>>(query, key_, value, abf);
        gemm256<false><<<dim3(32, 4, 3), dim3(512), 0, stream>>>(
            abf, abf + MN, abf + 2 * MN, Wq_bf, Wk_bf, Wv_bf, bq, bk, bv, Qb, Kb, Vb);
    } else {
        Qb = Wbf + 4 * WN; Kb = Qb + MN; Vb = Kb + MN;
        gemm128<true, false><<<dim3(64, 8, 3), dim3(256), 0, stream>>>(
            query, key_, value, Wq_bf, Wk_bf, Wv_bf, bq, bk, bv, Qb, Kb, Vb);
    }

    unsigned short* O2 = Qb;   // alias (safe, see attn_mfma)
    attn_mfma<<<dim3(1024, 2), dim3(512), 0, stream>>>(Qb, Kb, Vb, O2);

    gemm256<true><<<dim3(32, 4, 1), dim3(512), 0, stream>>>(
        O2, O2, O2, Wo_bf, Wo_bf, Wo_bf, bo, bo, bo, d_out, d_out, d_out);
}

// Round 3
// 287.593 us; speedup vs baseline: 1.0138x; 1.0138x over previous
//
#include <hip/hip_runtime.h>

// B=8, S=1024, D=1024, H=16, P=64. FP32 I/O, bf16 MFMA compute.
// convert W (+acts) -> bf16 | pipelined 256x256 QKV GEMM (4-slot, counted
// vmcnt, ASM ds_read) | MFMA batch-softmax attention | gemm128 final + sigmoid.

using short8   = __attribute__((ext_vector_type(8))) short;    // 8 bf16
using floatx4  = __attribute__((ext_vector_type(4))) float;    // MFMA acc 16x16
using floatx16 = __attribute__((ext_vector_type(16))) float;   // MFMA acc 32x32

__device__ __forceinline__ float bf2f(unsigned short u) {
    return __uint_as_float(((unsigned)u) << 16);
}
__device__ __forceinline__ unsigned short f2bf(float f) {   // RNE
    unsigned u = __float_as_uint(f);
    u += 0x7fffu + ((u >> 16) & 1u);
    return (unsigned short)(u >> 16);
}
// two fp32 -> packed bf16 pair (truncation) in one v_perm: lo16=f0, hi16=f1
__device__ __forceinline__ unsigned pack_trunc(float f0, float f1) {
    return __builtin_amdgcn_perm(__float_as_uint(f1), __float_as_uint(f0), 0x07060302u);
}
__device__ __forceinline__ void async_ld16(const void* g, void* l) {
    __builtin_amdgcn_global_load_lds(
        (const __attribute__((address_space(1))) unsigned int*)g,
        (__attribute__((address_space(3))) unsigned int*)l, 16, 0, 0);
}
// Inline-asm LDS read: opaque to SIInsertWaitcnts, so the compiler does NOT
// order it against in-flight global_load_lds (no forced vmcnt(0) drain).
// Our explicit VM*/LGKM0 discipline provides the ordering instead.
__device__ __forceinline__ short8 lds_read_b128(unsigned addr) {
    short8 r;
    asm volatile("ds_read_b128 %0, %1" : "=v"(r) : "v"(addr));
    return r;
}

// ---------------------------------------------------------------------------
// fp32 -> bf16 (RNE) converters
// ---------------------------------------------------------------------------
__device__ __forceinline__ void conv8(const float* src, unsigned short* d, size_t i) {
    float4 a = *(const float4*)(src + i);
    float4 b = *(const float4*)(src + i + 4);
    uint4 o;
    o.x = ((unsigned)f2bf(a.y) << 16) | f2bf(a.x);
    o.y = ((unsigned)f2bf(a.w) << 16) | f2bf(a.z);
    o.z = ((unsigned)f2bf(b.y) << 16) | f2bf(b.x);
    o.w = ((unsigned)f2bf(b.w) << 16) | f2bf(b.z);
    *(uint4*)(d + i) = o;
}

__global__ __launch_bounds__(256) void convert_weights(
    const float* __restrict__ w0, const float* __restrict__ w1,
    const float* __restrict__ w2, const float* __restrict__ w3,
    unsigned short* __restrict__ dst)
{
    const float* srcs[4] = {w0, w1, w2, w3};
    conv8(srcs[blockIdx.y], dst + (size_t)blockIdx.y * (1024u * 1024u),
          ((size_t)blockIdx.x * 256 + threadIdx.x) * 8);
}

__global__ __launch_bounds__(256) void convert_acts(
    const float* __restrict__ a0, const float* __restrict__ a1,
    const float* __restrict__ a2, unsigned short* __restrict__ dst)
{
    const float* srcs[3] = {a0, a1, a2};
    conv8(srcs[blockIdx.y], dst + (size_t)blockIdx.y * ((size_t)8192 * 1024),
          ((size_t)blockIdx.x * 256 + threadIdx.x) * 8);
}

// ---------------------------------------------------------------------------
// 128x128 GEMM (m97 structure). Used for the FINAL GEMM (N=1024 shape fits
// its 512-block grid; measured 11 us faster than the 128-block gemm256) and
// as the small-workspace fallback.
// ---------------------------------------------------------------------------
template<bool AF32, bool SIG>
__global__ __launch_bounds__(256) void gemm128(
    const void* __restrict__ A0, const void* __restrict__ A1, const void* __restrict__ A2,
    const unsigned short* __restrict__ W0, const unsigned short* __restrict__ W1,
    const unsigned short* __restrict__ W2,
    const float* __restrict__ b0, const float* __restrict__ b1, const float* __restrict__ b2,
    void* __restrict__ C0, void* __restrict__ C1, void* __restrict__ C2)
{
    const int z = blockIdx.z;
    const void* Ap = (z == 0) ? A0 : (z == 1) ? A1 : A2;
    const unsigned short* W = (z == 0) ? W0 : (z == 1) ? W1 : W2;
    const float* bias = (z == 0) ? b0 : (z == 1) ? b1 : b2;
    void* Cp = (z == 0) ? C0 : (z == 1) ? C1 : C2;

    constexpr int Kd = 1024, Nd = 1024;
    const int t = threadIdx.x;
    const int w = t >> 6, lane = t & 63;
    const int l15 = lane & 15, quad = lane >> 4;
    const int blockM = blockIdx.x * 128;
    const int blockN = blockIdx.y * 128;
    const int wy = w >> 1, wx = w & 1;

    __shared__ unsigned short Bs[128 * 32];
    constexpr int ABYTES = AF32 ? (128 * 32 * 4) : (128 * 32 * 2);
    __shared__ __align__(16) unsigned char AsRaw[ABYTES];
    float* AsF = (float*)AsRaw;
    unsigned short* AsB = (unsigned short*)AsRaw;

    const int br  = lane >> 2;
    const int bg  = (lane & 3) ^ (br & 3);
    const unsigned short* Bsrc0 = W + (size_t)(blockN + w * 32 + br) * Kd + bg * 8;
    const unsigned short* Bsrc1 = Bsrc0 + (size_t)16 * Kd;
    unsigned short* Bdst0 = &Bs[(w * 2 + 0) * 512];
    unsigned short* Bdst1 = &Bs[(w * 2 + 1) * 512];

    const int ar = lane >> 3;
    const int ag = (lane & 7) ^ (ar & 7);
    const float* AsrcF[4];
    float* AdstF[4];
    const unsigned short* AsrcB0 = nullptr; const unsigned short* AsrcB1 = nullptr;
    unsigned short* AdstB0 = nullptr; unsigned short* AdstB1 = nullptr;
    if (AF32) {
        #pragma unroll
        for (int j = 0; j < 4; ++j) {
            AsrcF[j] = (const float*)Ap + (size_t)(blockM + w * 32 + j * 8 + ar) * Kd + ag * 4;
            AdstF[j] = AsF + (w * 4 + j) * 256;
        }
    } else {
        AsrcB0 = (const unsigned short*)Ap + (size_t)(blockM + w * 32 + br) * Kd + bg * 8;
        AsrcB1 = AsrcB0 + (size_t)16 * Kd;
        AdstB0 = &AsB[(w * 2 + 0) * 512];
        AdstB1 = &AsB[(w * 2 + 1) * 512];
    }

    floatx4 acc[4][4] = {};

    for (int k0 = 0; k0 < Kd; k0 += 32) {
        if (AF32) {
            #pragma unroll
            for (int j = 0; j < 4; ++j) async_ld16(AsrcF[j] + k0, AdstF[j]);
        } else {
            async_ld16(AsrcB0 + k0, AdstB0);
            async_ld16(AsrcB1 + k0, AdstB1);
        }
        async_ld16(Bsrc0 + k0, Bdst0);
        async_ld16(Bsrc1 + k0, Bdst1);
        __syncthreads();

        short8 af[4], bfr[4];
        #pragma unroll
        for (int mt = 0; mt < 4; ++mt) {
            const int row = wy * 64 + mt * 16 + l15;
            if (AF32) {
                const int r7 = l15 & 7;
                const float* ap = AsF + row * 32;
                float4 lo = *(const float4*)(ap + (((quad * 2 + 0) ^ r7) * 4));
                float4 hi = *(const float4*)(ap + (((quad * 2 + 1) ^ r7) * 4));
                union { unsigned u[4]; short8 s; } cv;
                cv.u[0] = pack_trunc(lo.x, lo.y);
                cv.u[1] = pack_trunc(lo.z, lo.w);
                cv.u[2] = pack_trunc(hi.x, hi.y);
                cv.u[3] = pack_trunc(hi.z, hi.w);
                af[mt] = cv.s;
            } else {
                af[mt] = *(const short8*)&AsB[row * 32 + (quad ^ (l15 & 3)) * 8];
            }
        }
        #pragma unroll
        for (int nt = 0; nt < 4; ++nt) {
            const int row = wx * 64 + nt * 16 + l15;
            bfr[nt] = *(const short8*)&Bs[row * 32 + (quad ^ (l15 & 3)) * 8];
        }
        #pragma unroll
        for (int mt = 0; mt < 4; ++mt)
            #pragma unroll
            for (int nt = 0; nt < 4; ++nt)
                acc[mt][nt] = __builtin_amdgcn_mfma_f32_16x16x32_bf16(af[mt], bfr[nt], acc[mt][nt], 0, 0, 0);
        __syncthreads();
    }

    #pragma unroll
    for (int nt = 0; nt < 4; ++nt) {
        const int col = blockN + wx * 64 + nt * 16 + l15;
        const float bv = bias[col];
        #pragma unroll
        for (int mt = 0; mt < 4; ++mt) {
            const int row = blockM + wy * 64 + mt * 16 + quad * 4;
            #pragma unroll
            for (int r = 0; r < 4; ++r) {
                float v = acc[mt][nt][r] + bv;
                if (SIG) {
                    v = 1.0f / (1.0f + __expf(-v));
                    ((float*)Cp)[(size_t)(row + r) * Nd + col] = v;
                } else {
                    ((unsigned short*)Cp)[(size_t)(row + r) * Nd + col] = f2bf(v);
                }
            }
        }
    }
}

// ---------------------------------------------------------------------------
// 256x256-tile pipelined GEMM. C = A.W^T + bias, A bf16 [M][1024],
// W bf16 [N][1024]. BK=32, 4 LDS slots (128 KiB), 512 threads = 8 waves
// (2 M x 4 N), per-wave 128x64 output via mfma_f32_32x32x16_bf16 acc[4][2].
//
// Pipeline (phase t computes K-tile t from slot t&3, stages tile t+3):
//   [12 ASM ds_read_b128] [4 global_load_lds 16B -> slot (t+3)&3]
//   [s_waitcnt vmcnt(8)]  <- waits tile t+1 only; >=8 loads stay in flight
//   [s_barrier] [lgkmcnt(0)+sched_barrier] [setprio1; 16 MFMA; setprio0]
//   [s_barrier]
// ds_reads are inline asm so the compiler's waitcnt pass cannot see them as
// LDS accesses aliasing the in-flight LDS-DMA -> it no longer inserts a
// vmcnt(0) drain per phase (round-2 post-mortem). Ordering is manual:
//   - VM8 in phase t retires tile t+1's loads; barrier publishes to all
//     waves before phase t+1 reads slot (t+1)&3.
//   - LGKM0 completes all reads chip-wide before the barrier that precedes
//     the stage overwriting that slot (4 phases later).
// Tail: vmcnt steps 8 -> 4 -> 0 as staging stops.
//
// LDS layout per slot per matrix: 256 rows x 32 k, two rows per 128B line
// (L = r>>1), 16B granules swizzled G' = ((r&1)*4 + g) ^ (L&7); the inverse
// permutation is applied to the global source address (both-sides-or-
// neither), LDS dest stays linear per global_load_lds requirements.
// ---------------------------------------------------------------------------
#define VM8 do { asm volatile("s_waitcnt vmcnt(8)" ::: "memory"); \
                 __builtin_amdgcn_sched_barrier(0); } while (0)
#define VM4 do { asm volatile("s_waitcnt vmcnt(4)" ::: "memory"); \
                 __builtin_amdgcn_sched_barrier(0); } while (0)
#define VM0 do { asm volatile("s_waitcnt vmcnt(0)" ::: "memory"); \
                 __builtin_amdgcn_sched_barrier(0); } while (0)
#define LGKM0 do { asm volatile("s_waitcnt lgkmcnt(0)" ::: "memory"); \
                   __builtin_amdgcn_sched_barrier(0); } while (0)
#define BARRIER __builtin_amdgcn_s_barrier()

#define STAGE_T(s, k0) do { \
    async_ld16(srcA[0] + (k0), &lds[s][0][dA0]); \
    async_ld16(srcA[1] + (k0), &lds[s][0][dA1]); \
    async_ld16(srcB[0] + (k0), &lds[s][1][dA0]); \
    async_ld16(srcB[1] + (k0), &lds[s][1][dA1]); \
} while (0)

#define PHASE_T(s, STG, VMW) do { \
    const unsigned bA_ = (unsigned)(size_t)&lds[s][0][0]; \
    const unsigned bB_ = (unsigned)(size_t)&lds[s][1][0]; \
    short8 afr[4][2], bfr2[2][2]; \
    _Pragma("unroll") \
    for (int mf = 0; mf < 4; ++mf) \
      _Pragma("unroll") \
      for (int ks = 0; ks < 2; ++ks) \
        afr[mf][ks] = lds_read_b128(bA_ + (unsigned)aoffB[mf][ks]); \
    _Pragma("unroll") \
    for (int nf = 0; nf < 2; ++nf) \
      _Pragma("unroll") \
      for (int ks = 0; ks < 2; ++ks) \
        bfr2[nf][ks] = lds_read_b128(bB_ + (unsigned)boffB[nf][ks]); \
    STG; \
    VMW; \
    BARRIER; \
    LGKM0; \
    __builtin_amdgcn_s_setprio(1); \
    _Pragma("unroll") \
    for (int ks = 0; ks < 2; ++ks) \
      _Pragma("unroll") \
      for (int mf = 0; mf < 4; ++mf) \
        _Pragma("unroll") \
        for (int nf = 0; nf < 2; ++nf) \
          acc[mf][nf] = __builtin_amdgcn_mfma_f32_32x32x16_bf16( \
              afr[mf][ks], bfr2[nf][ks], acc[mf][nf], 0, 0, 0); \
    __builtin_amdgcn_s_setprio(0); \
    BARRIER; \
} while (0)

template<bool SIG>
__global__ __launch_bounds__(512, 2) void gemm256(
    const unsigned short* __restrict__ A0, const unsigned short* __restrict__ A1,
    const unsigned short* __restrict__ A2,
    const unsigned short* __restrict__ W0, const unsigned short* __restrict__ W1,
    const unsigned short* __restrict__ W2,
    const float* __restrict__ b0, const float* __restrict__ b1, const float* __restrict__ b2,
    void* __restrict__ C0, void* __restrict__ C1, void* __restrict__ C2)
{
    const int z = blockIdx.z;
    const unsigned short* A = (z == 0) ? A0 : (z == 1) ? A1 : A2;
    const unsigned short* W = (z == 0) ? W0 : (z == 1) ? W1 : W2;
    const float* bias = (z == 0) ? b0 : (z == 1) ? b1 : b2;
    void* Cp = (z == 0) ? C0 : (z == 1) ? C1 : C2;

    constexpr int Kd = 1024;
    const int t = threadIdx.x;
    const int w = t >> 6, l = t & 63;
    const int wy = w >> 2, wx = w & 3;          // 2 x 4 wave grid
    const int l31 = l & 31, h5 = l >> 5;
    const int blockM = blockIdx.x * 256;
    const int blockN = blockIdx.y * 256;

    __shared__ __align__(16) unsigned short lds[4][2][8192];  // 128 KiB

    // -- staging source pointers (inverse-swizzled global addresses) --
    // granule q = i*512 + w*64 + lane: L=q>>3, G'=q&7, Graw=G'^(L&7),
    // r = 2L + (Graw>>2), g = Graw&3  -> src elem (row0+r)*1024 + k0 + g*8
    const unsigned short* srcA[2];
    const unsigned short* srcB[2];
    #pragma unroll
    for (int i = 0; i < 2; ++i) {
        const int q  = i * 512 + w * 64 + l;
        const int L  = q >> 3;
        const int Gr = (q & 7) ^ (L & 7);
        const int r  = L * 2 + (Gr >> 2);
        const int g  = Gr & 3;
        srcA[i] = A + (size_t)(blockM + r) * Kd + g * 8;
        srcB[i] = W + (size_t)(blockN + r) * Kd + g * 8;
    }
    const int dA0 = (0 * 512 + w * 64) * 8;   // wave-uniform LDS short offsets
    const int dA1 = (1 * 512 + w * 64) * 8;

    // -- ds_read fragment byte offsets (swizzled) --
    // A-frag (32x32x16): row = m0 + l31, k = ks*16 + h5*8 + j
    const int Lh  = l31 >> 1;
    const int la7 = Lh & 7;
    const int e4  = (l & 1) * 4;
    int aoffB[4][2], boffB[2][2];
    #pragma unroll
    for (int mf = 0; mf < 4; ++mf)
        #pragma unroll
        for (int ks = 0; ks < 2; ++ks)
            aoffB[mf][ks] = ((wy * 64 + mf * 16 + Lh) * 64 + ((e4 + ks * 2 + h5) ^ la7) * 8) * 2;
    #pragma unroll
    for (int nf = 0; nf < 2; ++nf)
        #pragma unroll
        for (int ks = 0; ks < 2; ++ks)
            boffB[nf][ks] = ((wx * 32 + nf * 16 + Lh) * 64 + ((e4 + ks * 2 + h5) ^ la7) * 8) * 2;

    floatx16 acc[4][2] = {};

    // -- prologue: stage tiles 0,1,2; wait tile 0 --
    STAGE_T(0, 0); STAGE_T(1, 32); STAGE_T(2, 64);
    VM8;        // 12 outstanding -> wait tile 0 landed (t1,t2 in flight)
    BARRIER;

    int k0 = 96;
    #pragma unroll 1
    for (int tt = 0; tt < 28; tt += 4) {
        PHASE_T(0, STAGE_T(3, k0), VM8); k0 += 32;
        PHASE_T(1, STAGE_T(0, k0), VM8); k0 += 32;
        PHASE_T(2, STAGE_T(1, k0), VM8); k0 += 32;
        PHASE_T(3, STAGE_T(2, k0), VM8); k0 += 32;
    }
    // t = 28..31 (k0 == 992 stages tile 31)
    PHASE_T(0, STAGE_T(3, k0), VM8);
    PHASE_T(1, (void)0, VM4);
    PHASE_T(2, (void)0, VM0);
    PHASE_T(3, (void)0, (void)0);

    // -- epilogue: bias + store. C layout: col=l31, row=(rg&3)+8*(rg>>2)+4*h5
    const int colBase = blockN + wx * 64 + l31;
    const float bv0 = bias[colBase];
    const float bv1 = bias[colBase + 32];
    #pragma unroll
    for (int mf = 0; mf < 4; ++mf) {
        const int row0 = blockM + wy * 128 + mf * 32 + h5 * 4;
        #pragma unroll
        for (int nf = 0; nf < 2; ++nf) {
            const float bb = nf ? bv1 : bv0;
            const int col = colBase + nf * 32;
            #pragma unroll
            for (int rg = 0; rg < 16; ++rg) {
                const int row = row0 + (rg & 3) + 8 * (rg >> 2);
                float v = acc[mf][nf][rg] + bb;
                if (SIG) {
                    v = 1.0f / (1.0f + __expf(-v));
                    ((float*)Cp)[(size_t)row * 1024 + col] = v;
                } else {
                    ((unsigned short*)Cp)[(size_t)row * 1024 + col] = f2bf(v);
                }
            }
        }
    }
}

// ---------------------------------------------------------------------------
// MFMA attention. grid = (S=1024, 2 p-halves), block = 512 (wave = b).
// (unchanged — see earlier round comments)
// ---------------------------------------------------------------------------
__global__ __launch_bounds__(512) void attn_mfma(
    const unsigned short* __restrict__ Q,
    const unsigned short* __restrict__ Kt,
    const unsigned short* __restrict__ Vt,
    unsigned short* __restrict__ O2)
{
    constexpr int VOFF = 0;        // shorts
    constexpr int UOFF = 9216;     // shorts (16B-aligned: 18432 B)
    constexpr int QOFF = UOFF + 8192;
    __shared__ __align__(16) unsigned short lds[UOFF + 18432];

    const int s  = blockIdx.x;
    const int ph = blockIdx.y;
    const int t  = threadIdx.x;
    const int w  = t >> 6;          // wave = b
    const int l  = t & 63;
    const int l15 = l & 15, l31 = l & 31, half = l >> 5, quad = l >> 4;

    const size_t gb = ((size_t)w * 1024 + s) * 1024;  // shorts

    // ---- load phase ----
    {
        const unsigned* vg = (const unsigned*)(Vt + gb);
        unsigned* vd = (unsigned*)lds;            // Vt dword base
        #pragma unroll
        for (int it = 0; it < 8; ++it) {
            const int h = it * 2 + half;
            vd[w * 576 + h * 36 + l31] = vg[h * 32 + l31];
        }
        const unsigned short* kg = Kt + gb;
        unsigned* kd = (unsigned*)(lds + UOFF);
        #pragma unroll
        for (int h2 = 0; h2 < 8; ++h2) {
            unsigned klo = kg[(2 * h2) * 64 + l];
            unsigned khi = kg[(2 * h2 + 1) * 64 + l];
            kd[w * 512 + l * 8 + h2] = klo | (khi << 16);
        }
        const unsigned short* qg = Q + gb + ph * 32;
        unsigned* qd = (unsigned*)(lds + QOFF);
        #pragma unroll
        for (int it = 0; it < 4; ++it) {
            const int h = it * 4 + half * 2;
            unsigned qlo = qg[h * 64 + l31];
            unsigned qhi = qg[(h + 1) * 64 + l31];
            qd[w * 256 + l31 * 8 + it * 2 + half] = qlo | (qhi << 16);
        }
    }
    __syncthreads();

    // ---- scores: A=K (m=q), B=Q (n=p), K=16=h ----
    floatx16 sc[2];
    {
        short8 qf = *(const short8*)&lds[QOFF + w * 512 + l31 * 16 + half * 8];
        short8 kf0 = *(const short8*)&lds[UOFF + w * 1024 + l31 * 16 + half * 8];
        short8 kf1 = *(const short8*)&lds[UOFF + w * 1024 + (32 + l31) * 16 + half * 8];
        floatx16 z = {};
        sc[0] = __builtin_amdgcn_mfma_f32_32x32x16_bf16(kf0, qf, z, 0, 0, 0);
        sc[1] = __builtin_amdgcn_mfma_f32_32x32x16_bf16(kf1, qf, z, 0, 0, 0);
    }
    __syncthreads();   // K/Q region dead -> reuse as Sexp

    // ---- exp + Sexp[p][q] writes (p = l31, q from C layout) ----
    {
        unsigned short* sx = lds + UOFF + w * 2304 + l31 * 72;
        #pragma unroll
        for (int nt = 0; nt < 2; ++nt) {
            #pragma unroll
            for (int rg = 0; rg < 4; ++rg) {
                float e0 = __expf(sc[nt][4 * rg + 0] * 0.125f);
                float e1 = __expf(sc[nt][4 * rg + 1] * 0.125f);
                float e2 = __expf(sc[nt][4 * rg + 2] * 0.125f);
                float e3 = __expf(sc[nt][4 * rg + 3] * 0.125f);
                uint2 pk = { pack_trunc(e0, e1), pack_trunc(e2, e3) };
                const int q0 = nt * 32 + rg * 8 + half * 4;
                *(uint2*)&sx[q0] = pk;
            }
        }
    }
    __syncthreads();

    // ---- batch-softmax denominators: thread owns (p=t&31, q0=(t>>5)*4) ----
    {
        const int p  = t & 31;
        const int q0 = (t >> 5) * 4;
        unsigned short* base = lds + UOFF + p * 72 + q0;
        float fv[8][4];
        float den0 = 0.f, den1 = 0.f, den2 = 0.f, den3 = 0.f;
        #pragma unroll
        for (int b = 0; b < 8; ++b) {
            uint2 v = *(const uint2*)&base[b * 2304];
            fv[b][0] = bf2f((unsigned short)(v.x & 0xffff));
            fv[b][1] = bf2f((unsigned short)(v.x >> 16));
            fv[b][2] = bf2f((unsigned short)(v.y & 0xffff));
            fv[b][3] = bf2f((unsigned short)(v.y >> 16));
            den0 += fv[b][0]; den1 += fv[b][1]; den2 += fv[b][2]; den3 += fv[b][3];
        }
        const float r0 = __builtin_amdgcn_rcpf(den0);
        const float r1 = __builtin_amdgcn_rcpf(den1);
        const float r2 = __builtin_amdgcn_rcpf(den2);
        const float r3 = __builtin_amdgcn_rcpf(den3);
        #pragma unroll
        for (int b = 0; b < 8; ++b) {
            uint2 pk = { pack_trunc(fv[b][0] * r0, fv[b][1] * r1),
                         pack_trunc(fv[b][2] * r2, fv[b][3] * r3) };
            *(uint2*)&base[b * 2304] = pk;
        }
    }
    __syncthreads();

    // ---- PV: A=weights[p][q], B=Vt[h][q]; out[p][h] ----
    floatx4 o[2] = {};
    #pragma unroll
    for (int qc = 0; qc < 2; ++qc) {
        short8 vf = *(const short8*)&lds[VOFF + w * 1152 + l15 * 72 + qc * 32 + quad * 8];
        #pragma unroll
        for (int mt = 0; mt < 2; ++mt) {
            short8 wf = *(const short8*)&lds[UOFF + w * 2304 + (mt * 16 + l15) * 72 + qc * 32 + quad * 8];
            o[mt] = __builtin_amdgcn_mfma_f32_16x16x32_bf16(wf, vf, o[mt], 0, 0, 0);
        }
    }
    {
        unsigned short* ol = lds + UOFF + w * 2304 + l15 * 36;
        #pragma unroll
        for (int mt = 0; mt < 2; ++mt) {
            uint2 pk = { pack_trunc(o[mt][0], o[mt][1]), pack_trunc(o[mt][2], o[mt][3]) };
            *(uint2*)&ol[mt * 16 + quad * 4] = pk;
        }
    }
    __syncthreads();

    // ---- coalesced store: per wave (b), 256 dwords ----
    {
        unsigned* outdw = (unsigned*)O2;
        const unsigned* ol = (const unsigned*)(lds + UOFF + w * 2304);
        const size_t gdw = ((size_t)w * 1024 + s) * 512 + ph * 16;
        #pragma unroll
        for (int i = 0; i < 4; ++i) {
            const int d = i * 64 + l;
            const int h = d >> 4, pq = d & 15;
            outdw[gdw + h * 32 + pq] = ol[h * 18 + pq];
        }
    }
}

// ---------------------------------------------------------------------------
extern "C" void kernel_launch(void* const* d_in, const int* in_sizes, int n_in,
                              void* d_out, int out_size, void* d_ws, size_t ws_size,
                              hipStream_t stream) {
    const float* query = (const float*)d_in[0];
    const float* key_  = (const float*)d_in[1];
    const float* value = (const float*)d_in[2];
    const float* Wq = (const float*)d_in[3];
    const float* bq = (const float*)d_in[4];
    const float* Wk = (const float*)d_in[5];
    const float* bk = (const float*)d_in[6];
    const float* Wv = (const float*)d_in[7];
    const float* bv = (const float*)d_in[8];
    const float* Wo = (const float*)d_in[9];
    const float* bo = (const float*)d_in[10];

    const size_t WN = (size_t)1024 * 1024;
    const size_t MN = (size_t)8192 * 1024;

    unsigned short* Wbf = (unsigned short*)d_ws;
    unsigned short* Wq_bf = Wbf;
    unsigned short* Wk_bf = Wbf + WN;
    unsigned short* Wv_bf = Wbf + 2 * WN;
    unsigned short* Wo_bf = Wbf + 3 * WN;

    convert_weights<<<dim3(512, 4), dim3(256), 0, stream>>>(Wq, Wk, Wv, Wo, Wbf);

    const bool big = ws_size >= (4 * WN + 6 * MN) * sizeof(unsigned short); // 104 MB

    unsigned short* Qb; unsigned short* Kb; unsigned short* Vb;
    if (big) {
        unsigned short* abf = Wbf + 4 * WN;
        Qb = abf + 3 * MN; Kb = Qb + MN; Vb = Kb + MN;
        convert_acts<<<dim3(4096, 3), dim3(256), 0, stream>>>(query, key_, value, abf);
        gemm256<false><<<dim3(32, 4, 3), dim3(512), 0, stream>>>(
            abf, abf + MN, abf + 2 * MN, Wq_bf, Wk_bf, Wv_bf, bq, bk, bv, Qb, Kb, Vb);
    } else {
        Qb = Wbf + 4 * WN; Kb = Qb + MN; Vb = Kb + MN;
        gemm128<true, false><<<dim3(64, 8, 3), dim3(256), 0, stream>>>(
            query, key_, value, Wq_bf, Wk_bf, Wv_bf, bq, bk, bv, Qb, Kb, Vb);
    }

    unsigned short* O2 = Qb;   // alias (safe, see attn_mfma)
    attn_mfma<<<dim3(1024, 2), dim3(512), 0, stream>>>(Qb, Kb, Vb, O2);

    gemm128<false, true><<<dim3(64, 8, 1), dim3(256), 0, stream>>>(
        O2, O2, O2, Wo_bf, Wo_bf, Wo_bf, bo, bo, bo, d_out, d_out, d_out);
}